// Round 1
// baseline (344.407 us; speedup 1.0000x reference)
//
#include <hip/hip_runtime.h>
#include <hip/hip_bf16.h>

typedef __attribute__((ext_vector_type(8))) short short8;
typedef __attribute__((ext_vector_type(4))) float f32x4;

#define LD4(dst, v4) { dst[0]=(v4).x; dst[1]=(v4).y; dst[2]=(v4).z; dst[3]=(v4).w; }

// B=2, T=512, CM=256, CZ=128, H=16, DH=16
static __device__ __forceinline__ short f2bf(float f) {
    union { float f; unsigned u; } v; v.f = f;
    unsigned r = (v.u + 0x7FFFu + ((v.u >> 16) & 1u)) >> 16;
    return (short)r;
}

// ---------------- K0: precompute Wz' (bf16, MFMA-B-frag layout), A_h, C_h ----------------
// wzp layout: [m=4][lane=64][ii=8] with c = m*32 + (lane>>4)*8 + ii, h = lane&15
__global__ void k0_tables(const float* __restrict__ ln_g, const float* __restrict__ ln_b,
                          const float* __restrict__ Wz, short* __restrict__ wzp,
                          float* __restrict__ Ah, float* __restrict__ Ch) {
    int t = threadIdx.x;
    for (int idx = t; idx < 2048; idx += 256) {
        int m = idx >> 9, rem = idx & 511, l = rem >> 3, ii = rem & 7;
        int c = m * 32 + ((l >> 4) << 3) + ii, h = l & 15;
        wzp[idx] = f2bf(ln_g[c] * Wz[c * 16 + h]);
    }
    if (t < 16) {
        float a = 0.f, cc = 0.f;
        for (int c = 0; c < 128; ++c) {
            a  += ln_g[c] * Wz[c * 16 + t];
            cc += ln_b[c] * Wz[c * 16 + t];
        }
        Ah[t] = a; Ch[t] = cc;
    }
}

// ---------------- proj: Y[m][c] = bias[c] + sum_k X[m][k]*W[c][k], K=N=256 ----------------
// 32-row x 128-col tile per block; 4x4 register blocking per thread.
__global__ void proj_gemm(const float* __restrict__ X, const float* __restrict__ W,
                          const float* __restrict__ bias, float* __restrict__ Y, int M) {
    __shared__ float xs[256 * 36];   // [k][r], padded to 36 for bank spread + 16B align
    int bx = blockIdx.x;
    int rt = bx >> 1, ct = bx & 1;
    int t = threadIdx.x;
    int row_base = rt * 32;
    {
        int r = t >> 3, k0 = (t & 7) * 32;
        int row = row_base + r;
        if (row < M) {
            const float* xp = X + (size_t)row * 256 + k0;
            #pragma unroll
            for (int q = 0; q < 8; ++q) {
                float4 v = *(const float4*)(xp + q * 4);
                xs[(k0 + q * 4 + 0) * 36 + r] = v.x;
                xs[(k0 + q * 4 + 1) * 36 + r] = v.y;
                xs[(k0 + q * 4 + 2) * 36 + r] = v.z;
                xs[(k0 + q * 4 + 3) * 36 + r] = v.w;
            }
        } else {
            #pragma unroll
            for (int q = 0; q < 32; ++q) xs[(k0 + q) * 36 + r] = 0.f;
        }
    }
    __syncthreads();
    int c_base = ct * 128 + (t & 31) * 4;
    int r_base = (t >> 5) * 4;
    float acc[4][4];
    #pragma unroll
    for (int a = 0; a < 4; ++a)
        #pragma unroll
        for (int b = 0; b < 4; ++b) acc[a][b] = 0.f;
    for (int k = 0; k < 256; k += 4) {
        float w0[4], w1[4], w2[4], w3[4];
        { float4 v = *(const float4*)(W + (size_t)(c_base + 0) * 256 + k); LD4(w0, v); }
        { float4 v = *(const float4*)(W + (size_t)(c_base + 1) * 256 + k); LD4(w1, v); }
        { float4 v = *(const float4*)(W + (size_t)(c_base + 2) * 256 + k); LD4(w2, v); }
        { float4 v = *(const float4*)(W + (size_t)(c_base + 3) * 256 + k); LD4(w3, v); }
        #pragma unroll
        for (int kk = 0; kk < 4; ++kk) {
            float xl[4];
            float4 xv = *(const float4*)(&xs[(k + kk) * 36 + r_base]);
            LD4(xl, xv);
            #pragma unroll
            for (int ri = 0; ri < 4; ++ri) {
                acc[ri][0] += xl[ri] * w0[kk];
                acc[ri][1] += xl[ri] * w1[kk];
                acc[ri][2] += xl[ri] * w2[kk];
                acc[ri][3] += xl[ri] * w3[kk];
            }
        }
    }
    #pragma unroll
    for (int ri = 0; ri < 4; ++ri) {
        int row = row_base + r_base + ri;
        if (row < M) {
            float4 o;
            o.x = acc[ri][0] + (bias ? bias[c_base + 0] : 0.f);
            o.y = acc[ri][1] + (bias ? bias[c_base + 1] : 0.f);
            o.z = acc[ri][2] + (bias ? bias[c_base + 2] : 0.f);
            o.w = acc[ri][3] + (bias ? bias[c_base + 3] : 0.f);
            *(float4*)(Y + (size_t)row * 256 + c_base) = o;
        }
    }
}

// ---------------- K2: z_bias via MFMA.  zb[b][i][h][j] fp32 ----------------
// one wave = 16 consecutive (b,i,j)-rows (fixed b,i; j-tile of 16)
__global__ void k2_zbias(const float* __restrict__ z, const short* __restrict__ wzp,
                         const float* __restrict__ Ah, const float* __restrict__ Ch,
                         float* __restrict__ zb) {
    int wave = threadIdx.x >> 6, lane = threadIdx.x & 63;
    int tile = blockIdx.x * 4 + wave;
    int row0 = tile * 16;
    int b = row0 >> 18;
    int i = (row0 >> 9) & 511;
    int j0 = row0 & 511;
    int r = lane & 15, g = lane >> 4;
    const float* zr = z + (size_t)(row0 + r) * 128 + g * 8;
    float sum = 0.f, sq = 0.f;
    short8 af[4];
    #pragma unroll
    for (int m = 0; m < 4; ++m) {
        float4 a = *(const float4*)(zr + m * 32);
        float4 c = *(const float4*)(zr + m * 32 + 4);
        sum += a.x + a.y + a.z + a.w + c.x + c.y + c.z + c.w;
        sq  += a.x*a.x + a.y*a.y + a.z*a.z + a.w*a.w + c.x*c.x + c.y*c.y + c.z*c.z + c.w*c.w;
        short8 s;
        s[0]=f2bf(a.x); s[1]=f2bf(a.y); s[2]=f2bf(a.z); s[3]=f2bf(a.w);
        s[4]=f2bf(c.x); s[5]=f2bf(c.y); s[6]=f2bf(c.z); s[7]=f2bf(c.w);
        af[m] = s;
    }
    f32x4 acc = {0.f, 0.f, 0.f, 0.f};
    #pragma unroll
    for (int m = 0; m < 4; ++m) {
        short8 bw = *(const short8*)(wzp + m * 512 + lane * 8);
        acc = __builtin_amdgcn_mfma_f32_16x16x32_bf16(af[m], bw, acc, 0, 0, 0);
    }
    // per-row stats: lanes {l, l^16, l^32, l^48} share row (l&15)
    sum += __shfl_xor(sum, 16); sum += __shfl_xor(sum, 32);
    sq  += __shfl_xor(sq, 16);  sq  += __shfl_xor(sq, 32);
    float mu = sum * (1.f / 128.f);
    float var = sq * (1.f / 128.f) - mu * mu;
    float rs = rsqrtf(var + 1e-5f);
    int h = lane & 15;
    float ah = Ah[h], ch = Ch[h];
    size_t base = ((size_t)((b * 512 + i) * 16 + h)) * 512 + j0;
    #pragma unroll
    for (int reg = 0; reg < 4; ++reg) {
        int orow = g * 4 + reg;                 // j-offset within tile (D row)
        float mo = __shfl(mu, orow);
        float ro = __shfl(rs, orow);
        zb[base + orow] = ro * (acc[reg] - mo * ah) + ch;
    }
}

// ---------------- K3: scores[b][h][i][j] = mask ? -1e4 : (content+pos)/4 + zb ----------------
__global__ void k3_scores(const float* __restrict__ q, const float* __restrict__ kmat,
                          const float* __restrict__ p,
                          const float* __restrict__ u_bias, const float* __restrict__ v_bias,
                          const float* __restrict__ zb, const int* __restrict__ mask,
                          float* __restrict__ sc) {
    int bx = blockIdx.x;
    int b = bx >> 8, h = (bx >> 4) & 15, it = bx & 15;
    int i0 = it * 32;
    int t = threadIdx.x;
    int j0 = 2 * t, j1 = 2 * t + 1;
    float kr0[16], kr1[16], uu[16], vv[16];
    {
        const float* kp0 = kmat + (size_t)(b * 512 + j0) * 256 + h * 16;
        #pragma unroll
        for (int d = 0; d < 4; ++d) {
            { float4 v = *(const float4*)(kp0 + d * 4);        LD4((&kr0[d*4]), v); }
            { float4 v = *(const float4*)(kp0 + 256 + d * 4);  LD4((&kr1[d*4]), v); }
            { float4 v = *(const float4*)(u_bias + h * 16 + d * 4); LD4((&uu[d*4]), v); }
            { float4 v = *(const float4*)(v_bias + h * 16 + d * 4); LD4((&vv[d*4]), v); }
        }
    }
    int m0 = mask[b * 512 + j0], m1 = mask[b * 512 + j1];
    for (int i = i0; i < i0 + 32; ++i) {
        const float* qp = q + (size_t)(b * 512 + i) * 256 + h * 16;
        const float* pr = p + ((size_t)(b * 1023 + 511 + j0 - i)) * 256 + h * 16;
        float c0 = 0.f, c1 = 0.f, p0 = 0.f, p1 = 0.f;
        #pragma unroll
        for (int d = 0; d < 4; ++d) {
            float ql[4], pal[4], pbl[4];
            { float4 v = *(const float4*)(qp + d * 4);        LD4(ql, v); }
            { float4 v = *(const float4*)(pr + d * 4);        LD4(pal, v); }
            { float4 v = *(const float4*)(pr + 256 + d * 4);  LD4(pbl, v); }
            #pragma unroll
            for (int e = 0; e < 4; ++e) {
                int d4 = d * 4 + e;
                float qu = ql[e] + uu[d4];
                float qv = ql[e] + vv[d4];
                c0 += qu * kr0[d4];
                c1 += qu * kr1[d4];
                p0 += qv * pal[e];
                p1 += qv * pbl[e];
            }
        }
        const float* zp = zb + ((size_t)((b * 512 + i) * 16 + h)) * 512 + j0;
        float z0 = zp[0], z1 = zp[1];
        float s0 = m0 ? -10000.f : (c0 + p0) * 0.25f + z0;
        float s1 = m1 ? -10000.f : (c1 + p1) * 0.25f + z1;
        float2 o; o.x = s0; o.y = s1;
        *(float2*)(sc + ((size_t)((b * 16 + h) * 512 + i)) * 512 + j0) = o;
    }
}

// ---------------- K4: row softmax, write bf16 attn ----------------
__global__ void k4_softmax(const float* __restrict__ sc, short* __restrict__ attn) {
    int wave = threadIdx.x >> 6, lane = threadIdx.x & 63;
    size_t row = (size_t)blockIdx.x * 4 + wave;
    const float* sp = sc + row * 512 + lane * 8;
    float x[8];
    { float4 v = *(const float4*)sp;       LD4(x, v); }
    { float4 v = *(const float4*)(sp + 4); LD4((&x[4]), v); }
    float m = x[0];
    #pragma unroll
    for (int j = 1; j < 8; ++j) m = fmaxf(m, x[j]);
    #pragma unroll
    for (int off = 32; off >= 1; off >>= 1) m = fmaxf(m, __shfl_xor(m, off));
    float s = 0.f;
    #pragma unroll
    for (int j = 0; j < 8; ++j) { x[j] = __expf(x[j] - m); s += x[j]; }
    #pragma unroll
    for (int off = 32; off >= 1; off >>= 1) s += __shfl_xor(s, off);
    float inv = 1.f / s;
    short8 o;
    #pragma unroll
    for (int j = 0; j < 8; ++j) o[j] = f2bf(x[j] * inv);
    *(short8*)(attn + row * 512 + lane * 8) = o;
}

// ---------------- K5: ctx[b][i][h*16+dh] = sum_j attn[b,h,i,j] * v[b,j,h,dh] (MFMA) ----------------
__global__ void k5_ctx(const short* __restrict__ attn, const float* __restrict__ v,
                       float* __restrict__ ctx) {
    int bx = blockIdx.x; int b = bx >> 4, h = bx & 15;
    int wave = threadIdx.x >> 6, lane = threadIdx.x & 63;
    int colbase = h * 16 + (lane & 15);
    short8 bf[16];
    #pragma unroll
    for (int kb = 0; kb < 16; ++kb) {
        short8 s;
        #pragma unroll
        for (int ii = 0; ii < 8; ++ii) {
            int j = kb * 32 + (lane >> 4) * 8 + ii;
            s[ii] = f2bf(v[(size_t)(b * 512 + j) * 256 + colbase]);
        }
        bf[kb] = s;
    }
    for (int qq = 0; qq < 8; ++qq) {
        int i0 = (wave * 8 + qq) * 16;
        f32x4 acc = {0.f, 0.f, 0.f, 0.f};
        const short* ap = attn + ((size_t)((b * 16 + h) * 512 + i0 + (lane & 15))) * 512 + (lane >> 4) * 8;
        #pragma unroll
        for (int kb = 0; kb < 16; ++kb) {
            short8 a = *(const short8*)(ap + kb * 32);
            acc = __builtin_amdgcn_mfma_f32_16x16x32_bf16(a, bf[kb], acc, 0, 0, 0);
        }
        #pragma unroll
        for (int reg = 0; reg < 4; ++reg) {
            int i = i0 + (lane >> 4) * 4 + reg;
            ctx[(size_t)(b * 512 + i) * 256 + h * 16 + (lane & 15)] = acc[reg];
        }
    }
}

extern "C" void kernel_launch(void* const* d_in, const int* in_sizes, int n_in,
                              void* d_out, int out_size, void* d_ws, size_t ws_size,
                              hipStream_t stream) {
    const float* query = (const float*)d_in[0];
    const float* key   = (const float*)d_in[1];
    const float* value = (const float*)d_in[2];
    const float* pos   = (const float*)d_in[3];
    const float* z     = (const float*)d_in[4];
    const int*   mask  = (const int*)d_in[5];
    const float* Wq = (const float*)d_in[6];
    const float* bq = (const float*)d_in[7];
    const float* Wk = (const float*)d_in[8];
    const float* bk = (const float*)d_in[9];
    const float* Wv = (const float*)d_in[10];
    const float* bv = (const float*)d_in[11];
    const float* Wp = (const float*)d_in[12];
    const float* u_bias = (const float*)d_in[13];
    const float* v_bias = (const float*)d_in[14];
    const float* Wo = (const float*)d_in[15];
    const float* bo = (const float*)d_in[16];
    const float* ln_g = (const float*)d_in[17];
    const float* ln_b = (const float*)d_in[18];
    const float* Wz = (const float*)d_in[19];

    char* ws = (char*)d_ws;
    float* qb  = (float*)(ws + 0);                // 1 MB
    float* kb_ = (float*)(ws + (1u << 20));       // 1 MB
    float* vb_ = (float*)(ws + (2u << 20));       // 1 MB
    float* pb  = (float*)(ws + (3u << 20));       // 2046*1024 B
    short* wzp = (short*)(ws + 5242880);          // 4 KB
    float* Ah  = (float*)(ws + 5242880 + 4096);
    float* Ch  = (float*)(ws + 5242880 + 4096 + 64);
    float* zbp = (float*)(ws + (8u << 20));       // 33.5 MB
    float* scp = (float*)(ws + 41943040ull);      // 33.5 MB
    short* attn = (short*)(ws + (8u << 20));      // reuse zb region (dead after k3)
    float* ctx  = (float*)(ws + 75497472ull);     // 2 MB

    hipLaunchKernelGGL(k0_tables, dim3(1), dim3(256), 0, stream, ln_g, ln_b, Wz, wzp, Ah, Ch);
    hipLaunchKernelGGL(proj_gemm, dim3(64),  dim3(256), 0, stream, query, Wq, bq, qb, 1024);
    hipLaunchKernelGGL(proj_gemm, dim3(64),  dim3(256), 0, stream, key,   Wk, bk, kb_, 1024);
    hipLaunchKernelGGL(proj_gemm, dim3(64),  dim3(256), 0, stream, value, Wv, bv, vb_, 1024);
    hipLaunchKernelGGL(proj_gemm, dim3(128), dim3(256), 0, stream, pos,   Wp, (const float*)nullptr, pb, 2046);
    hipLaunchKernelGGL(k2_zbias, dim3(8192), dim3(256), 0, stream, z, wzp, Ah, Ch, zbp);
    hipLaunchKernelGGL(k3_scores, dim3(512), dim3(256), 0, stream, qb, kb_, pb, u_bias, v_bias, zbp, mask, scp);
    hipLaunchKernelGGL(k4_softmax, dim3(4096), dim3(256), 0, stream, scp, attn);
    hipLaunchKernelGGL(k5_ctx, dim3(32), dim3(256), 0, stream, attn, vb_, ctx);
    hipLaunchKernelGGL(proj_gemm, dim3(64), dim3(256), 0, stream, ctx, Wo, bo, (float*)d_out, 1024);
}

// Round 2
// 225.665 us; speedup vs baseline: 1.5262x; 1.5262x over previous
//
#include <hip/hip_runtime.h>
#include <hip/hip_bf16.h>

typedef __attribute__((ext_vector_type(8))) short short8;
typedef __attribute__((ext_vector_type(4))) short short4v;
typedef __attribute__((ext_vector_type(4))) float f32x4;

#define LD4(dst, v4) { dst[0]=(v4).x; dst[1]=(v4).y; dst[2]=(v4).z; dst[3]=(v4).w; }

// B=2, T=512, CM=256, CZ=128, H=16, DH=16
static __device__ __forceinline__ short f2bf(float f) {
    union { float f; unsigned u; } v; v.f = f;
    unsigned r = (v.u + 0x7FFFu + ((v.u >> 16) & 1u)) >> 16;
    return (short)r;
}

// ---------------- shared proj tile: Y[m][c] = bias[c] + sum_k X[m][k]*W[c][k] ----------------
// 32-row x 128-col tile; base = tile id (2 col tiles per 32-row strip). fp32 or bf16 output.
static __device__ __forceinline__ void proj_tile(
    const float* __restrict__ X, const float* __restrict__ W,
    const float* __restrict__ bias, float* __restrict__ Yf,
    short* __restrict__ Yb, int M, int base, float* xs)
{
    int rt = base >> 1, ct = base & 1;
    int t = threadIdx.x;
    int row_base = rt * 32;
    {
        int r = t >> 3, k0 = (t & 7) * 32;
        int row = row_base + r;
        if (row < M) {
            const float* xp = X + (size_t)row * 256 + k0;
            #pragma unroll
            for (int q = 0; q < 8; ++q) {
                float4 v = *(const float4*)(xp + q * 4);
                xs[(k0 + q * 4 + 0) * 36 + r] = v.x;
                xs[(k0 + q * 4 + 1) * 36 + r] = v.y;
                xs[(k0 + q * 4 + 2) * 36 + r] = v.z;
                xs[(k0 + q * 4 + 3) * 36 + r] = v.w;
            }
        } else {
            #pragma unroll
            for (int q = 0; q < 32; ++q) xs[(k0 + q) * 36 + r] = 0.f;
        }
    }
    __syncthreads();
    int c_base = ct * 128 + (t & 31) * 4;
    int r_base = (t >> 5) * 4;
    float acc[4][4];
    #pragma unroll
    for (int a = 0; a < 4; ++a)
        #pragma unroll
        for (int b = 0; b < 4; ++b) acc[a][b] = 0.f;
    for (int k = 0; k < 256; k += 4) {
        float w0[4], w1[4], w2[4], w3[4];
        { float4 v = *(const float4*)(W + (size_t)(c_base + 0) * 256 + k); LD4(w0, v); }
        { float4 v = *(const float4*)(W + (size_t)(c_base + 1) * 256 + k); LD4(w1, v); }
        { float4 v = *(const float4*)(W + (size_t)(c_base + 2) * 256 + k); LD4(w2, v); }
        { float4 v = *(const float4*)(W + (size_t)(c_base + 3) * 256 + k); LD4(w3, v); }
        #pragma unroll
        for (int kk = 0; kk < 4; ++kk) {
            float xl[4];
            float4 xv = *(const float4*)(&xs[(k + kk) * 36 + r_base]);
            LD4(xl, xv);
            #pragma unroll
            for (int ri = 0; ri < 4; ++ri) {
                acc[ri][0] += xl[ri] * w0[kk];
                acc[ri][1] += xl[ri] * w1[kk];
                acc[ri][2] += xl[ri] * w2[kk];
                acc[ri][3] += xl[ri] * w3[kk];
            }
        }
    }
    #pragma unroll
    for (int ri = 0; ri < 4; ++ri) {
        int row = row_base + r_base + ri;
        if (row < M) {
            float o0 = acc[ri][0] + (bias ? bias[c_base + 0] : 0.f);
            float o1 = acc[ri][1] + (bias ? bias[c_base + 1] : 0.f);
            float o2 = acc[ri][2] + (bias ? bias[c_base + 2] : 0.f);
            float o3 = acc[ri][3] + (bias ? bias[c_base + 3] : 0.f);
            if (Yb) {
                short4v o; o[0] = f2bf(o0); o[1] = f2bf(o1); o[2] = f2bf(o2); o[3] = f2bf(o3);
                *(short4v*)(Yb + (size_t)row * 256 + c_base) = o;
            } else {
                float4 o; o.x = o0; o.y = o1; o.z = o2; o.w = o3;
                *(float4*)(Yf + (size_t)row * 256 + c_base) = o;
            }
        }
    }
}

// ---------------- fused: q/k/v/p projections + wzp/Ah/Ch tables, one launch ----------------
__global__ void proj_all(const float* __restrict__ query, const float* __restrict__ key,
                         const float* __restrict__ value, const float* __restrict__ pos,
                         const float* __restrict__ Wq, const float* __restrict__ bq,
                         const float* __restrict__ Wk, const float* __restrict__ bk,
                         const float* __restrict__ Wv, const float* __restrict__ bv,
                         const float* __restrict__ Wp,
                         const float* __restrict__ ln_g, const float* __restrict__ ln_b,
                         const float* __restrict__ Wz,
                         float* __restrict__ qb, short* __restrict__ kbf,
                         float* __restrict__ vb, short* __restrict__ pbf,
                         short* __restrict__ wzp, float* __restrict__ Ah, float* __restrict__ Ch)
{
    __shared__ float xs[256 * 36];
    int bx = blockIdx.x;
    if (bx == 320) {
        int t = threadIdx.x;
        for (int idx = t; idx < 2048; idx += 256) {
            int m = idx >> 9, rem = idx & 511, l = rem >> 3, ii = rem & 7;
            int c = m * 32 + ((l >> 4) << 3) + ii, h = l & 15;
            wzp[idx] = f2bf(ln_g[c] * Wz[c * 16 + h]);
        }
        if (t < 16) {
            float a = 0.f, cc = 0.f;
            for (int c = 0; c < 128; ++c) {
                a  += ln_g[c] * Wz[c * 16 + t];
                cc += ln_b[c] * Wz[c * 16 + t];
            }
            Ah[t] = a; Ch[t] = cc;
        }
        return;
    }
    if (bx < 64)       proj_tile(query, Wq, bq, qb, nullptr, 1024, bx, xs);
    else if (bx < 128) proj_tile(key,   Wk, bk, nullptr, kbf, 1024, bx - 64, xs);
    else if (bx < 192) proj_tile(value, Wv, bv, vb, nullptr, 1024, bx - 128, xs);
    else               proj_tile(pos,   Wp, nullptr, nullptr, pbf, 2046, bx - 192, xs);
}

__global__ void proj_o(const float* __restrict__ X, const float* __restrict__ W,
                       const float* __restrict__ bias, float* __restrict__ Y)
{
    __shared__ float xs[256 * 36];
    proj_tile(X, W, bias, Y, nullptr, 1024, blockIdx.x, xs);
}

// ---------------- mega: z->zbias + scores(MFMA) + softmax + ctx, one block per (b,i) --------
// score[j][h] = 0.25*((q+u)·k + (q+v)·p_rel) + rs*(accz - mu*Ah) + Ch, then softmax over j,
// then ctx[c] = sum_j attn[h(c)][j] * v[b,j,c].
__global__ void __launch_bounds__(256) k_attn(
    const float* __restrict__ z, const short* __restrict__ wzp,
    const float* __restrict__ Ah, const float* __restrict__ Ch,
    const float* __restrict__ qb, const short* __restrict__ kbf,
    const short* __restrict__ pbf, const float* __restrict__ vb,
    const float* __restrict__ u_bias, const float* __restrict__ v_bias,
    const int* __restrict__ mask, float* __restrict__ ctx)
{
    __shared__ float w_lds[512 * 17];   // scores -> exp weights, [j][h] stride 17
    __shared__ float red_max[64];
    __shared__ float red_sum[64];
    const short8 zero8 = {0, 0, 0, 0, 0, 0, 0, 0};

    int bid = blockIdx.x;
    int b = bid >> 9, i = bid & 511;
    int t = threadIdx.x;
    int lane = t & 63, wave = t >> 6;
    int h = lane & 15, g = lane >> 4;

    // B-fragments: wzp (z-bias weights) and sparse Qu/Qv (content/pos weights)
    short8 wz[4];
    #pragma unroll
    for (int m = 0; m < 4; ++m) wz[m] = *(const short8*)(wzp + m * 512 + lane * 8);
    float ah = Ah[h], ch = Ch[h];

    bool act = ((h & 1) == (g >> 1));       // this lane's B-slot hits h's diag block?
    int m_act = act ? (h >> 1) : 8;         // which of the 8 K-steps is nonzero
    short8 qu8 = zero8, qv8 = zero8;
    {
        int c0 = h * 16 + (g & 1) * 8;      // always valid
        const float* qp = qb + (size_t)(b * 512 + i) * 256 + c0;
        #pragma unroll
        for (int ii = 0; ii < 8; ++ii) {
            float qv_ = qp[ii];
            qu8[ii] = f2bf(0.25f * (qv_ + u_bias[c0 + ii]));
            qv8[ii] = f2bf(0.25f * (qv_ + v_bias[c0 + ii]));
        }
        if (!act) { qu8 = zero8; qv8 = zero8; }
    }

    const float* zb_ = z + (size_t)((b * 512 + i) * 512) * 128;
    int jw = wave * 128;                     // this wave's 128-j strip
    float mloc = -3.0e38f;

    for (int tile = 0; tile < 8; ++tile) {
        int jbase = jw + tile * 16;
        int jr = jbase + h;                  // A-frag row this lane loads
        const float* zr = zb_ + (size_t)jr * 128 + g * 8;
        float sum = 0.f, sq = 0.f;
        f32x4 accz = {0.f, 0.f, 0.f, 0.f};
        #pragma unroll
        for (int m = 0; m < 4; ++m) {
            float4 a = *(const float4*)(zr + m * 32);
            float4 c = *(const float4*)(zr + m * 32 + 4);
            sum += a.x + a.y + a.z + a.w + c.x + c.y + c.z + c.w;
            sq  += a.x*a.x + a.y*a.y + a.z*a.z + a.w*a.w + c.x*c.x + c.y*c.y + c.z*c.z + c.w*c.w;
            short8 s8;
            s8[0] = f2bf(a.x); s8[1] = f2bf(a.y); s8[2] = f2bf(a.z); s8[3] = f2bf(a.w);
            s8[4] = f2bf(c.x); s8[5] = f2bf(c.y); s8[6] = f2bf(c.z); s8[7] = f2bf(c.w);
            accz = __builtin_amdgcn_mfma_f32_16x16x32_bf16(s8, wz[m], accz, 0, 0, 0);
        }
        sum += __shfl_xor(sum, 16); sum += __shfl_xor(sum, 32);
        sq  += __shfl_xor(sq, 16);  sq  += __shfl_xor(sq, 32);
        float mu = sum * (1.f / 128.f);
        float rs = rsqrtf(sq * (1.f / 128.f) - mu * mu + 1e-5f);

        f32x4 acp = {0.f, 0.f, 0.f, 0.f};
        const short* kr = kbf + (size_t)(b * 512 + jr) * 256 + g * 8;
        const short* pr = pbf + (size_t)(b * 1023 + 511 + jr - i) * 256 + g * 8;
        #pragma unroll
        for (int m = 0; m < 8; ++m) {
            short8 ka = *(const short8*)(kr + m * 32);
            short8 pa = *(const short8*)(pr + m * 32);
            short8 bu = (m == m_act) ? qu8 : zero8;
            short8 bv = (m == m_act) ? qv8 : zero8;
            acp = __builtin_amdgcn_mfma_f32_16x16x32_bf16(ka, bu, acp, 0, 0, 0);
            acp = __builtin_amdgcn_mfma_f32_16x16x32_bf16(pa, bv, acp, 0, 0, 0);
        }
        int mrow = mask[b * 512 + jr];
        #pragma unroll
        for (int reg = 0; reg < 4; ++reg) {
            int joff = g * 4 + reg;
            float mo = __shfl(mu, joff);
            float ro = __shfl(rs, joff);
            int   mk = __shfl(mrow, joff);
            float s = acp[reg] + ro * (accz[reg] - mo * ah) + ch;
            s = mk ? -10000.f : s;
            mloc = fmaxf(mloc, s);
            w_lds[(jbase + joff) * 17 + h] = s;
        }
    }

    // softmax over j per h
    mloc = fmaxf(mloc, __shfl_xor(mloc, 16));
    mloc = fmaxf(mloc, __shfl_xor(mloc, 32));
    if (lane < 16) red_max[wave * 16 + lane] = mloc;
    __syncthreads();
    float mg = fmaxf(fmaxf(red_max[h], red_max[16 + h]), fmaxf(red_max[32 + h], red_max[48 + h]));
    float ssum = 0.f;
    #pragma unroll
    for (int tile = 0; tile < 8; ++tile) {
        #pragma unroll
        for (int reg = 0; reg < 4; ++reg) {
            int j = jw + tile * 16 + g * 4 + reg;
            float e = __expf(w_lds[j * 17 + h] - mg);
            ssum += e;
            w_lds[j * 17 + h] = e;
        }
    }
    ssum += __shfl_xor(ssum, 16); ssum += __shfl_xor(ssum, 32);
    if (lane < 16) red_sum[wave * 16 + lane] = ssum;
    __syncthreads();

    // ctx: thread t owns output channel c=t, h2 = c>>4; coalesced v reads per j
    int h2 = t >> 4;
    float sg = red_sum[h2] + red_sum[16 + h2] + red_sum[32 + h2] + red_sum[48 + h2];
    float inv = 1.f / sg;
    const float* vcol = vb + (size_t)(b * 512) * 256 + t;
    float acc = 0.f;
    #pragma unroll 8
    for (int j = 0; j < 512; ++j) acc += w_lds[j * 17 + h2] * vcol[(size_t)j * 256];
    ctx[(size_t)(b * 512 + i) * 256 + t] = acc * inv;
}

extern "C" void kernel_launch(void* const* d_in, const int* in_sizes, int n_in,
                              void* d_out, int out_size, void* d_ws, size_t ws_size,
                              hipStream_t stream) {
    const float* query = (const float*)d_in[0];
    const float* key   = (const float*)d_in[1];
    const float* value = (const float*)d_in[2];
    const float* pos   = (const float*)d_in[3];
    const float* z     = (const float*)d_in[4];
    const int*   mask  = (const int*)d_in[5];
    const float* Wq = (const float*)d_in[6];
    const float* bq = (const float*)d_in[7];
    const float* Wk = (const float*)d_in[8];
    const float* bk = (const float*)d_in[9];
    const float* Wv = (const float*)d_in[10];
    const float* bv = (const float*)d_in[11];
    const float* Wp = (const float*)d_in[12];
    const float* u_bias = (const float*)d_in[13];
    const float* v_bias = (const float*)d_in[14];
    const float* Wo = (const float*)d_in[15];
    const float* bo = (const float*)d_in[16];
    const float* ln_g = (const float*)d_in[17];
    const float* ln_b = (const float*)d_in[18];
    const float* Wz = (const float*)d_in[19];

    char* ws = (char*)d_ws;
    float* qb  = (float*)(ws + 0);               // 1 MB fp32
    float* vb  = (float*)(ws + (1u << 20));      // 1 MB fp32
    short* kbf = (short*)(ws + (2u << 20));      // 512 KB bf16
    short* pbf = (short*)(ws + (2u << 20) + (512u << 10)); // ~1 MB bf16
    short* wzp = (short*)(ws + (4u << 20));      // 4 KB
    float* Ah  = (float*)(ws + (4u << 20) + 4096);
    float* Ch  = (float*)(ws + (4u << 20) + 4096 + 64);
    float* ctx = (float*)(ws + (5u << 20));      // 1 MB fp32

    hipLaunchKernelGGL(proj_all, dim3(321), dim3(256), 0, stream,
                       query, key, value, pos, Wq, bq, Wk, bk, Wv, bv, Wp,
                       ln_g, ln_b, Wz, qb, kbf, vb, pbf, wzp, Ah, Ch);
    hipLaunchKernelGGL(k_attn, dim3(1024), dim3(256), 0, stream,
                       z, wzp, Ah, Ch, qb, kbf, pbf, vb, u_bias, v_bias, mask, ctx);
    hipLaunchKernelGGL(proj_o, dim3(64), dim3(256), 0, stream, ctx, Wo, bo, (float*)d_out);
}